// Round 6
// baseline (249.772 us; speedup 1.0000x reference)
//
#include <hip/hip_runtime.h>
#include <hip/hip_bf16.h>

// N=4, C=256, H=W=64 -> HW=4096, E=128, 3E=384.
// qkv flat [n][o][hw] IS [n][p][384]: q=p*384+0..127, k=+128, v=+256.
// attn flat [n][i*128+d] reinterpreted as [n][e][hw] by k_oproj (raw reshape).
// Column softmax (over i): scores s=q.k/64, |s|<~1.2 -> direct sum-exp (no max).
// R14 = R13 with the Vt dbuf stride bug fixed: each Vt buffer is 16384 B
//      (128 rows x 128 B), NOT 32768. R13 indexed cur*32768, so odd-cur V reads
//      aliased Pl and even-cur stage writes stomped Pl -> absmax 440 (matches
//      unnormalized-sum magnitude: 5 sigma of sqrt(4096)-walk ~ 325-450).
//      Everything else identical to R13: 32x32x16 MFMA, swizzled LDS, P via LDS.

typedef short bfrag __attribute__((ext_vector_type(8)));   // 8 bf16 (4 VGPRs)
typedef float ffrag __attribute__((ext_vector_type(4)));   // 4 fp32 acc (16x16)
typedef float ffrag16 __attribute__((ext_vector_type(16)));// 16 fp32 acc (32x32)
typedef unsigned short us4 __attribute__((ext_vector_type(4)));
#define MFMA(a,b,c)   __builtin_amdgcn_mfma_f32_16x16x32_bf16((a),(b),(c),0,0,0)
#define MFMA32(a,b,c) __builtin_amdgcn_mfma_f32_32x32x16_bf16((a),(b),(c),0,0,0)

__device__ __forceinline__ unsigned short f2bf(float f){
  union { float f; unsigned u; } v; v.f = f;
  unsigned r = v.u + 0x7fffu + ((v.u >> 16) & 1u);   // RNE
  return (unsigned short)(r >> 16);
}
__device__ __forceinline__ float bf2f(unsigned short h){
  union { unsigned u; float f; } v; v.u = ((unsigned)h) << 16; return v.f;
}
__device__ __forceinline__ unsigned bfpack(float a, float b){
  return (unsigned)f2bf(a) | ((unsigned)f2bf(b) << 16);
}

// ---------------- K0: cast weights to bf16 ----------------
__global__ __launch_bounds__(256) void k_wcast(const float* __restrict__ Wq, const float* __restrict__ Wo,
                                               unsigned short* __restrict__ Wqb, unsigned short* __restrict__ Wob){
  int i = blockIdx.x*256 + threadIdx.x;
  if (i < 384*256) Wqb[i] = f2bf(Wq[i]);
  if (i < 256*128) Wob[i] = f2bf(Wo[i]);
}

// ---------------- K1: QKV projection, o-tile 128 (x re-read 3x instead of 6x) ----------------
__global__ __launch_bounds__(256) void k_qkv(const float* __restrict__ x, const unsigned short* __restrict__ Wqb,
                                             const float* __restrict__ bq, unsigned short* __restrict__ qkv){
  constexpr int LD = 136;
  __shared__ __align__(16) unsigned short As[128*LD];  // W tile [o 128][c-half 128]  34816 B
  __shared__ __align__(16) unsigned short Bs[64*LD];   // X^T tile [hw 64][c-half]    17408 B
  const int o0 = blockIdx.x*128, h0 = blockIdx.y*64, n = blockIdx.z;
  const int t = threadIdx.x, w = t>>6, lane = t&63, lr = lane&15, q4 = lane>>4;
  ffrag acc[8] = {};
  for (int kh = 0; kh < 2; ++kh) {
    __syncthreads();
    #pragma unroll
    for (int r=0;r<8;++r){                       // 2048 = 128 o x 16 segs
      int pi = t + 256*r; int o = pi>>4, seg = pi&15;
      *(uint4*)&As[o*LD + seg*8] = *(const uint4*)(Wqb + (o0+o)*256 + kh*128 + seg*8);
    }
    #pragma unroll
    for (int r=0;r<8;++r){                       // 2048 = 128 c x 16 h-quads, float4 loads
      int idx = t + 256*r; int cl = idx>>4, h4 = idx&15;
      float4 v = *(const float4*)(x + (size_t)(n*256 + kh*128 + cl)*4096 + h0 + h4*4);
      Bs[(h4*4+0)*LD + cl] = f2bf(v.x);
      Bs[(h4*4+1)*LD + cl] = f2bf(v.y);
      Bs[(h4*4+2)*LD + cl] = f2bf(v.z);
      Bs[(h4*4+3)*LD + cl] = f2bf(v.w);
    }
    __syncthreads();
    #pragma unroll
    for (int kk=0;kk<4;++kk){
      bfrag a = *(const bfrag*)&Bs[(w*16+lr)*LD + kk*32 + q4*8];   // A = x^T rows (hw)
      #pragma unroll
      for (int ot=0;ot<8;++ot){
        bfrag b = *(const bfrag*)&As[(ot*16+lr)*LD + kk*32 + q4*8]; // B = W rows (o)
        acc[ot] = MFMA(a,b,acc[ot]);                                // D[m=hw][n=o]
      }
    }
  }
  size_t base = (size_t)n*384*4096;
  #pragma unroll
  for (int ot=0;ot<8;++ot){
    int o  = o0 + ot*16 + lr;
    float bias = bq[o];
    int hw = h0 + w*16 + q4*4;
    us4 pk;
    pk.x = f2bf(acc[ot][0] + bias); pk.y = f2bf(acc[ot][1] + bias);
    pk.z = f2bf(acc[ot][2] + bias); pk.w = f2bf(acc[ot][3] + bias);
    *(us4*)(qkv + base + (size_t)o*4096 + hw) = pk;
  }
}

// ---------------- K2: column Z partials, wave owns 64 j (16 reg K-frags, 4 MFMA per Q read) ----------------
__global__ __launch_bounds__(256) void k_stats(const unsigned short* __restrict__ qkv,
                                               float* __restrict__ zp){
  constexpr int LD = 136;
  __shared__ __align__(16) unsigned short Qs[64*LD];   // 17408 B
  const int j0 = blockIdx.x*256, ic = blockIdx.y, n = blockIdx.z;
  const int t = threadIdx.x, w = t>>6, lane = t&63, lr = lane&15, q4 = lane>>4;
  size_t base = (size_t)n*384*4096;
  bfrag kf[4][4];
  #pragma unroll
  for (int js=0; js<4; ++js){
    const unsigned short* krow = qkv + base + (size_t)(j0 + w*64 + js*16 + lr)*384 + 128;
    #pragma unroll
    for (int kk=0;kk<4;++kk) kf[js][kk] = *(const bfrag*)(krow + kk*32 + q4*8);
  }
  float Zc[16] = {};                      // [js*4 + r]
  const float inv64 = 0.015625f;
  for (int rnd=0; rnd<8; ++rnd){          // 8 x 64-i stage rounds (ic chunk = 512 i)
    int i0 = (ic<<9) + rnd*64;
    __syncthreads();
    #pragma unroll
    for (int r=0;r<4;++r){
      int pi = t + 256*r; int il = pi>>4, seg = pi&15;
      *(uint4*)&Qs[il*LD + seg*8] = *(const uint4*)(qkv + base + (size_t)(i0+il)*384 + seg*8);
    }
    __syncthreads();
    #pragma unroll
    for (int it=0; it<4; ++it){
      bfrag qb[4];
      #pragma unroll
      for (int kk=0;kk<4;++kk) qb[kk] = *(const bfrag*)&Qs[(it*16+lr)*LD + kk*32 + q4*8];
      #pragma unroll
      for (int js=0; js<4; ++js){
        ffrag s = {};
        #pragma unroll
        for (int kk=0;kk<4;++kk) s = MFMA(kf[js][kk], qb[kk], s);   // D[m=j][n=i]
        #pragma unroll
        for (int r=0;r<4;++r) Zc[js*4+r] += __expf(s[r]*inv64);
      }
    }
  }
  #pragma unroll
  for (int v=0; v<16; ++v){
    float z = Zc[v];
    z += __shfl_xor(z, 1); z += __shfl_xor(z, 2);
    z += __shfl_xor(z, 4); z += __shfl_xor(z, 8);
    Zc[v] = z;
  }
  if (lr == 0){
    int jb = j0 + w*64;
    float* zrow = zp + (size_t)((n<<3)+ic)*4096;
    #pragma unroll
    for (int js=0; js<4; ++js)
      #pragma unroll
      for (int r=0;r<4;++r)
        zrow[jb + js*16 + q4*4 + r] = Zc[js*4+r];
  }
}

// ---------------- K3: V transpose + Z-merge + 1/Z fold: vt[n][d][p] = v[n][p][d] / Z[p] ----------------
__global__ __launch_bounds__(256) void k_vtrans(const unsigned short* __restrict__ qkv,
                                                const float* __restrict__ zp,
                                                unsigned short* __restrict__ vt){
  constexpr int LD = 136;
  __shared__ __align__(16) unsigned short T[64*LD];
  __shared__ float invZ[64];
  const int p0 = blockIdx.x*64, n = blockIdx.y;
  const int t = threadIdx.x;
  size_t base = (size_t)n*384*4096;
  #pragma unroll
  for (int r=0;r<4;++r){
    int pi = t + 256*r; int pl = pi>>4, seg = pi&15;
    *(uint4*)&T[pl*LD + seg*8] = *(const uint4*)(qkv + base + (size_t)(p0+pl)*384 + 256 + seg*8);
  }
  if (t < 64){                            // merge zp partials for this block's 64 j
    float Z = 0.f;
    #pragma unroll
    for (int c=0;c<8;++c) Z += zp[(size_t)((n<<3)+c)*4096 + p0 + t];
    invZ[t] = 1.0f / Z;
  }
  __syncthreads();
  unsigned* vt32 = (unsigned*)(vt + (size_t)n*128*4096);
  #pragma unroll
  for (int r=0;r<16;++r){
    int pi = t + 256*r;            // 4096 = 128 d x 32 p-pairs
    int d = pi>>5, k = pi&31;
    float lo = bf2f(T[(2*k)*LD + d])   * invZ[2*k];
    float hi = bf2f(T[(2*k+1)*LD + d]) * invZ[2*k+1];
    vt32[(size_t)d*2048 + (p0>>1) + k] = bfpack(lo, hi);
  }
}

// ---------------- K4: PV pass — 32x32x16 MFMA, swizzled LDS, P via LDS [i][j] ----------------
__global__ __launch_bounds__(256, 2) void k_attn(const unsigned short* __restrict__ qkv,
                                                 const unsigned short* __restrict__ vtg_all,
                                                 unsigned short* __restrict__ part){
  __shared__ __align__(16) unsigned short Ks[64*128];      // 16 KB  [j][d] swz
  __shared__ __align__(16) unsigned short Vt[2][128*64];   // 2 x 16 KB  [d][j] swz, dbuf
  __shared__ __align__(16) unsigned short Pl[128*64];      // 16 KB  [i][j] swz    total 64 KB
  constexpr int VBUF = 16384;             // bytes per Vt buffer (128 rows x 128 B)
  const int i0 = blockIdx.x*128, jh = blockIdx.y, n = blockIdx.z;
  const int t = threadIdx.x, w = t>>6, lane = t&63, l31 = lane&31, hi = lane>>5, l7 = lane&7;
  const int jw = w&1, iw = w>>1;          // QK^T: j-half / i-half; PV: d-half = jw, same iw
  size_t base = (size_t)n*384*4096;
  const unsigned short* vtg = vtg_all + (size_t)n*128*4096;
  char* KsB = (char*)Ks;
  char* VtB = (char*)Vt;                  // buffer b at VtB + b*VBUF
  char* PlB = (char*)Pl;

  // Q fragments, register-resident: B[k=d][n=i]; lane: col i = tile+l31, k = hi*8..+8
  bfrag qf[2][8];
  #pragma unroll
  for (int it2=0; it2<2; ++it2){
    const unsigned short* qrow = qkv + base + (size_t)(i0 + iw*64 + it2*32 + l31)*384;
    #pragma unroll
    for (int kk=0;kk<8;++kk) qf[it2][kk] = *(const bfrag*)(qrow + kk*16 + hi*8);
  }

  // staging geometry: K rows 256 B (thread t covers row t>>4 (+16r), 16 B at (t&15)*16)
  //                   V rows 128 B (thread t covers row t>>3 (+32r), 16 B at (t&7)*16)
  const int krow_l = t>>4, kcol = (t&15)*16;
  const int vrow_l = t>>3, vcol = (t&7)*16;

  // prologue: stage tile 0 (swizzled: LDS byte-in-row ^= (row&7)<<4)
  {
    const int j0 = jh*1024;
    #pragma unroll
    for (int r=0;r<4;++r){
      int row = krow_l + 16*r;
      uint4 kv = *(const uint4*)(qkv + base + (size_t)(j0+row)*384 + 128 + (kcol>>1));
      *(uint4*)(KsB + row*256 + (kcol ^ ((row&7)*16))) = kv;
    }
    #pragma unroll
    for (int r=0;r<4;++r){
      int d = vrow_l + 32*r;
      uint4 vv = *(const uint4*)(vtg + (size_t)d*4096 + j0 + (vcol>>1));
      *(uint4*)(VtB + d*128 + (vcol ^ ((d&7)*16))) = vv;
    }
  }
  __syncthreads();

  ffrag16 acc[2][2] = {};                 // [dt][it] 32x32 out tiles (64 f32)
  const float inv64 = 0.015625f;

  for (int it=0; it<16; ++it){
    const int cur = it&1;
    // (1) early-issue next tile's global loads (consumed in step 4, after mid barrier)
    uint4 kr[4], vr[4];
    if (it < 15){
      const int jn = jh*1024 + (it+1)*64;
      #pragma unroll
      for (int r=0;r<4;++r){
        int row = krow_l + 16*r;
        kr[r] = *(const uint4*)(qkv + base + (size_t)(jn+row)*384 + 128 + (kcol>>1));
      }
      #pragma unroll
      for (int r=0;r<4;++r){
        int d = vrow_l + 32*r;
        vr[r] = *(const uint4*)(vtg + (size_t)d*4096 + jn + (vcol>>1));
      }
    }
    // (2) QK^T: A[m=j 32]=K from LDS, B=Q regs; D[m=j][n=i]  (8 reads, 16 MFMA)
    ffrag16 s0 = {}, s1 = {};
    #pragma unroll
    for (int kk=0;kk<8;++kk){
      bfrag kf = *(const bfrag*)(KsB + (jw*32+l31)*256 + ((kk*32 + hi*16) ^ (l7*16)));
      s0 = MFMA32(kf, qf[0][kk], s0);
      s1 = MFMA32(kf, qf[1][kk], s1);
    }
    // (3) exp + pack j-pairs + write P to LDS [i][j] (16 b32 writes)
    //     D row j = jw*32 + (reg&3) + 8*(reg>>2) + 4*hi; regs (2m,2m+1) are j,j+1
    #pragma unroll
    for (int m=0;m<8;++m){
      const int joff = 2*(m&1) + 8*(m>>1) + 4*hi;
      const int cswz = (2*(jw*32 + joff)) ^ (l7*16);
      unsigned p0 = bfpack(__expf(s0[2*m]*inv64), __expf(s0[2*m+1]*inv64));
      unsigned p1 = bfpack(__expf(s1[2*m]*inv64), __expf(s1[2*m+1]*inv64));
      *(unsigned*)(PlB + (iw*64      + l31)*128 + cswz) = p0;
      *(unsigned*)(PlB + (iw*64 + 32 + l31)*128 + cswz) = p1;
    }
    __syncthreads();                      // P visible to all waves; Ks fully consumed
    // (4) sink staged next-tile K (same buffer, now free) and V (other buffer)
    if (it < 15){
      #pragma unroll
      for (int r=0;r<4;++r){
        int row = krow_l + 16*r;
        *(uint4*)(KsB + row*256 + (kcol ^ ((row&7)*16))) = kr[r];
      }
      #pragma unroll
      for (int r=0;r<4;++r){
        int d = vrow_l + 32*r;
        *(uint4*)(VtB + (cur^1)*VBUF + d*128 + (vcol ^ ((d&7)*16))) = vr[r];
      }
    }
    // (5) PV: A[m=d]=Vt[cur], B[k=j][n=i]=P  (8+8 reads, 16 MFMA)
    #pragma unroll
    for (int jk=0;jk<4;++jk){
      const int cswz = (jk*32 + hi*16) ^ (l7*16);
      bfrag pb0 = *(const bfrag*)(PlB + (iw*64      + l31)*128 + cswz);
      bfrag pb1 = *(const bfrag*)(PlB + (iw*64 + 32 + l31)*128 + cswz);
      bfrag vf0 = *(const bfrag*)(VtB + cur*VBUF + (jw*64      + l31)*128 + cswz);
      bfrag vf1 = *(const bfrag*)(VtB + cur*VBUF + (jw*64 + 32 + l31)*128 + cswz);
      acc[0][0] = MFMA32(vf0, pb0, acc[0][0]);   // D[m=d][n=i]
      acc[0][1] = MFMA32(vf0, pb1, acc[0][1]);
      acc[1][0] = MFMA32(vf1, pb0, acc[1][0]);
      acc[1][1] = MFMA32(vf1, pb1, acc[1][1]);
    }
    __syncthreads();                      // Pl/Vt[cur] consumed; staged writes visible
  }

  // epilogue: D row d = (reg&3)+8*(reg>>2)+4*hi -> regs 4g..4g+3 are d-contiguous
  unsigned short* po = part + (size_t)(jh*4+n)*524288;
  #pragma unroll
  for (int it2=0; it2<2; ++it2){
    const int i = i0 + iw*64 + it2*32 + l31;
    #pragma unroll
    for (int dt=0; dt<2; ++dt){
      #pragma unroll
      for (int g=0; g<4; ++g){
        int d = jw*64 + dt*32 + g*8 + 4*hi;
        us4 pko;
        pko.x = f2bf(acc[dt][it2][4*g+0]); pko.y = f2bf(acc[dt][it2][4*g+1]);
        pko.z = f2bf(acc[dt][it2][4*g+2]); pko.w = f2bf(acc[dt][it2][4*g+3]);
        *(us4*)(po + (size_t)i*128 + d) = pko;
      }
    }
  }
}

// ---------------- K5: output projection, sums 4 bf16 partial slices (uint4 loads), c-tile 128 ----------------
__global__ __launch_bounds__(256) void k_oproj(const unsigned short* __restrict__ part,
                                               const unsigned short* __restrict__ Wob,
                                               const float* __restrict__ bo, float* __restrict__ y){
  constexpr int LD = 136;
  __shared__ __align__(16) unsigned short As[128*LD];  // Wo tile [c][e]
  __shared__ __align__(16) unsigned short Rt[64*LD];   // attn^T [hw][e]
  const int c0 = blockIdx.x*128, h0 = blockIdx.y*64, n = blockIdx.z;
  const int t = threadIdx.x, w = t>>6, lane = t&63, lr = lane&15, q4 = lane>>4;
  #pragma unroll
  for (int r=0;r<8;++r){
    int pi = t + 256*r; int cl = pi>>4, seg = pi&15;
    *(uint4*)&As[cl*LD + seg*8] = *(const uint4*)(Wob + (c0+cl)*128 + seg*8);
  }
  #pragma unroll
  for (int r=0;r<4;++r){                     // 1024 = 128 e x 8 h-octets, uint4 loads
    int pi = t + 256*r; int e = pi>>3, h8 = pi&7;
    size_t f = (size_t)e*4096 + h0 + h8*8;
    float a[8] = {};
    #pragma unroll
    for (int s=0;s<4;++s){
      uint4 u = *(const uint4*)(part + (size_t)(s*4+n)*524288 + f);
      a[0] += bf2f((unsigned short)(u.x & 0xffffu)); a[1] += bf2f((unsigned short)(u.x >> 16));
      a[2] += bf2f((unsigned short)(u.y & 0xffffu)); a[3] += bf2f((unsigned short)(u.y >> 16));
      a[4] += bf2f((unsigned short)(u.z & 0xffffu)); a[5] += bf2f((unsigned short)(u.z >> 16));
      a[6] += bf2f((unsigned short)(u.w & 0xffffu)); a[7] += bf2f((unsigned short)(u.w >> 16));
    }
    #pragma unroll
    for (int k=0;k<8;++k) Rt[(h8*8+k)*LD + e] = f2bf(a[k]);
  }
  __syncthreads();
  ffrag acc[8] = {};
  #pragma unroll
  for (int kk=0;kk<4;++kk){
    bfrag a = *(const bfrag*)&Rt[(w*16+lr)*LD + kk*32 + q4*8];   // A = attn^T rows (hw)
    #pragma unroll
    for (int cs=0;cs<8;++cs){
      bfrag b = *(const bfrag*)&As[(cs*16+lr)*LD + kk*32 + q4*8]; // B = Wo rows (c)
      acc[cs] = MFMA(a,b,acc[cs]);                                // D[m=hw][n=c]
    }
  }
  #pragma unroll
  for (int cs=0;cs<8;++cs){
    int c = c0 + cs*16 + lr;
    float bias = bo[c];
    float4 v4 = { acc[cs][0]+bias, acc[cs][1]+bias, acc[cs][2]+bias, acc[cs][3]+bias };
    *(float4*)(y + ((size_t)n*256 + c)*4096 + h0 + w*16 + q4*4) = v4;
  }
}

extern "C" void kernel_launch(void* const* d_in, const int* in_sizes, int n_in,
                              void* d_out, int out_size, void* d_ws, size_t ws_size,
                              hipStream_t stream){
  const float* x  = (const float*)d_in[0];
  const float* Wq = (const float*)d_in[1];
  const float* bq = (const float*)d_in[2];
  const float* Wo = (const float*)d_in[3];
  const float* bo = (const float*)d_in[4];
  float* y = (float*)d_out;
  char* ws = (char*)d_ws;
  unsigned short* qkv  = (unsigned short*)(ws + 0);          // 12,582,912
  unsigned short* vtg  = (unsigned short*)(ws + 12582912);   //  4,194,304
  unsigned short* Wqb  = (unsigned short*)(ws + 16777216);   //    196,608
  unsigned short* Wob  = (unsigned short*)(ws + 16973824);   //     65,536
  float* zp   = (float*)(ws + 17039360);                     //    524,288 (4n x 8ic x 4096)
  unsigned short* part = (unsigned short*)(ws + 17629184);   // 16,777,216 (16 bf16 slices jh*4+n)

  k_wcast <<<dim3(384),     256, 0, stream>>>(Wq, Wo, Wqb, Wob);
  k_qkv   <<<dim3(3,64,4),  256, 0, stream>>>(x, Wqb, bq, qkv);
  k_stats <<<dim3(16,8,4),  256, 0, stream>>>(qkv, zp);
  k_vtrans<<<dim3(64,4),    256, 0, stream>>>(qkv, zp, vtg);
  k_attn  <<<dim3(32,4,4),  256, 0, stream>>>(qkv, vtg, part);
  k_oproj <<<dim3(2,64,4),  256, 0, stream>>>(part, Wob, bo, y);
}

// Round 8
// 182.211 us; speedup vs baseline: 1.3708x; 1.3708x over previous
//
#include <hip/hip_runtime.h>
#include <hip/hip_bf16.h>

// N=4, C=256, H=W=64 -> HW=4096, E=128, 3E=384.
// qkv flat [n][o][hw] IS [n][p][384]: q=p*384+0..127, k=+128, v=+256.
// attn flat [n][i*128+d] reinterpreted as [n][e][hw] by k_oproj (raw reshape).
// Column softmax (over i): scores s=q.k/64, |s|<~1.2 -> direct sum-exp (no max).
// R16 = R15 resubmit (round 7 was an infra failure: "container failed twice";
//      the kernel never ran). k_attn = R4/R12 verbatim (best measured: 56.3us).
//      Pipeline changes vs R4 baseline: (1) k_wcast removed -- W cast folded into
//      As staging of k_qkv/k_oproj (fp32 + f2bf). (2) Bs/Rt column-writes were
//      8-way bank conflicted (lane row-step 4/8 rows x 272B); fixed with granule
//      XOR keyed (row>>3)&7 on write AND fragment-read sides. (3) k_stats:
//      single-barrier double-buffered Q staging + launch_bounds(256,2).

typedef short bfrag __attribute__((ext_vector_type(8)));   // 8 bf16 (4 VGPRs)
typedef float ffrag __attribute__((ext_vector_type(4)));   // 4 fp32 acc
typedef unsigned short us4 __attribute__((ext_vector_type(4)));
#define MFMA(a,b,c) __builtin_amdgcn_mfma_f32_16x16x32_bf16((a),(b),(c),0,0,0)

__device__ __forceinline__ unsigned short f2bf(float f){
  union { float f; unsigned u; } v; v.f = f;
  unsigned r = v.u + 0x7fffu + ((v.u >> 16) & 1u);   // RNE
  return (unsigned short)(r >> 16);
}
__device__ __forceinline__ float bf2f(unsigned short h){
  union { unsigned u; float f; } v; v.u = ((unsigned)h) << 16; return v.f;
}
__device__ __forceinline__ unsigned bfpack(float a, float b){
  return (unsigned)f2bf(a) | ((unsigned)f2bf(b) << 16);
}

// ---------------- K1: QKV projection; W cast fused into As staging; Bs swizzled ----------------
__global__ __launch_bounds__(256) void k_qkv(const float* __restrict__ x, const float* __restrict__ Wq,
                                             const float* __restrict__ bq, unsigned short* __restrict__ qkv){
  constexpr int LD = 136;                              // 272 B rows
  __shared__ __align__(16) unsigned short As[128*LD];  // W tile [o 128][c-half 128]
  __shared__ __align__(16) unsigned short Bs[64*LD];   // X^T tile [hw 64][c-half], swizzled
  char* BsB = (char*)Bs;
  const int o0 = blockIdx.x*128, h0 = blockIdx.y*64, n = blockIdx.z;
  const int t = threadIdx.x, w = t>>6, lane = t&63, lr = lane&15, q4 = lane>>4;
  ffrag acc[8] = {};
  for (int kh = 0; kh < 2; ++kh) {
    __syncthreads();
    #pragma unroll
    for (int r=0;r<8;++r){                       // 2048 = 128 o x 16 segs, cast from fp32
      int pi = t + 256*r; int o = pi>>4, seg = pi&15;
      const float* wsrc = Wq + (size_t)(o0+o)*256 + kh*128 + seg*8;
      float4 w0 = *(const float4*)(wsrc);
      float4 w1 = *(const float4*)(wsrc+4);
      us4 lo, hv;
      lo.x=f2bf(w0.x); lo.y=f2bf(w0.y); lo.z=f2bf(w0.z); lo.w=f2bf(w0.w);
      hv.x=f2bf(w1.x); hv.y=f2bf(w1.y); hv.z=f2bf(w1.z); hv.w=f2bf(w1.w);
      *(us4*)&As[o*LD + seg*8]     = lo;
      *(us4*)&As[o*LD + seg*8 + 4] = hv;
    }
    #pragma unroll
    for (int r=0;r<8;++r){                       // X^T staging, swizzled column writes
      int idx = t + 256*r; int cl = idx>>4, h4 = idx&15;
      float4 v = *(const float4*)(x + (size_t)(n*256 + kh*128 + cl)*4096 + h0 + h4*4);
      float vv[4] = {v.x, v.y, v.z, v.w};
      #pragma unroll
      for (int u=0;u<4;++u){
        int row = h4*4+u;
        *(unsigned short*)(BsB + row*272 + ((2*cl) ^ (((row>>3)&7)<<4))) = f2bf(vv[u]);
      }
    }
    __syncthreads();
    const int arow = w*16+lr;
    const int akey = ((arow>>3)&7)<<4;
    #pragma unroll
    for (int kk=0;kk<4;++kk){
      bfrag a = *(const bfrag*)(BsB + arow*272 + ((kk*64 + q4*16) ^ akey));  // A = x^T rows (hw)
      #pragma unroll
      for (int ot=0;ot<8;++ot){
        bfrag b = *(const bfrag*)&As[(ot*16+lr)*LD + kk*32 + q4*8]; // B = W rows (o)
        acc[ot] = MFMA(a,b,acc[ot]);                                // D[m=hw][n=o]
      }
    }
  }
  size_t base = (size_t)n*384*4096;
  #pragma unroll
  for (int ot=0;ot<8;++ot){
    int o  = o0 + ot*16 + lr;
    float bias = bq[o];
    int hw = h0 + w*16 + q4*4;
    us4 pk;
    pk.x = f2bf(acc[ot][0] + bias); pk.y = f2bf(acc[ot][1] + bias);
    pk.z = f2bf(acc[ot][2] + bias); pk.w = f2bf(acc[ot][3] + bias);
    *(us4*)(qkv + base + (size_t)o*4096 + hw) = pk;
  }
}

// ---------------- K2: column Z partials; dbuf Q staging, 1 barrier/round ----------------
__global__ __launch_bounds__(256, 2) void k_stats(const unsigned short* __restrict__ qkv,
                                                  float* __restrict__ zp){
  constexpr int LD = 136;
  __shared__ __align__(16) unsigned short Qs[2][64*LD];   // 2 x 17408 B
  const int j0 = blockIdx.x*256, ic = blockIdx.y, n = blockIdx.z;
  const int t = threadIdx.x, w = t>>6, lane = t&63, lr = lane&15, q4 = lane>>4;
  size_t base = (size_t)n*384*4096;
  bfrag kf[4][4];
  #pragma unroll
  for (int js=0; js<4; ++js){
    const unsigned short* krow = qkv + base + (size_t)(j0 + w*64 + js*16 + lr)*384 + 128;
    #pragma unroll
    for (int kk=0;kk<4;++kk) kf[js][kk] = *(const bfrag*)(krow + kk*32 + q4*8);
  }
  const int il = t>>4, seg = t&15;
  {
    const int i0 = (ic<<9);
    #pragma unroll
    for (int r=0;r<4;++r)
      *(uint4*)&Qs[0][(il+16*r)*LD + seg*8] =
        *(const uint4*)(qkv + base + (size_t)(i0+il+16*r)*384 + seg*8);
  }
  __syncthreads();
  float Zc[16] = {};                      // [js*4 + r]
  const float inv64 = 0.015625f;
  for (int rnd=0; rnd<8; ++rnd){          // 8 x 64-i rounds (ic chunk = 512 i)
    const int cur = rnd&1;
    uint4 qr[4];
    if (rnd<7){                           // issue next round's loads first
      const int i1 = (ic<<9) + (rnd+1)*64;
      #pragma unroll
      for (int r=0;r<4;++r)
        qr[r] = *(const uint4*)(qkv + base + (size_t)(i1+il+16*r)*384 + seg*8);
    }
    const unsigned short* qs = Qs[cur];
    #pragma unroll
    for (int it=0; it<4; ++it){
      bfrag qb[4];
      #pragma unroll
      for (int kk=0;kk<4;++kk) qb[kk] = *(const bfrag*)&qs[(it*16+lr)*LD + kk*32 + q4*8];
      #pragma unroll
      for (int js=0; js<4; ++js){
        ffrag s = {};
        #pragma unroll
        for (int kk=0;kk<4;++kk) s = MFMA(kf[js][kk], qb[kk], s);   // D[m=j][n=i]
        #pragma unroll
        for (int r=0;r<4;++r) Zc[js*4+r] += __expf(s[r]*inv64);
      }
    }
    if (rnd<7){                           // sink staged writes, one barrier per round
      #pragma unroll
      for (int r=0;r<4;++r) *(uint4*)&Qs[cur^1][(il+16*r)*LD + seg*8] = qr[r];
      __syncthreads();
    }
  }
  #pragma unroll
  for (int v=0; v<16; ++v){
    float z = Zc[v];
    z += __shfl_xor(z, 1); z += __shfl_xor(z, 2);
    z += __shfl_xor(z, 4); z += __shfl_xor(z, 8);
    Zc[v] = z;
  }
  if (lr == 0){
    int jb = j0 + w*64;
    float* zrow = zp + (size_t)((n<<3)+ic)*4096;
    #pragma unroll
    for (int js=0; js<4; ++js)
      #pragma unroll
      for (int r=0;r<4;++r)
        zrow[jb + js*16 + q4*4 + r] = Zc[js*4+r];
  }
}

// ---------------- K3: V transpose + Z-merge + 1/Z fold: vt[n][d][p] = v[n][p][d] / Z[p] ----------------
__global__ __launch_bounds__(256) void k_vtrans(const unsigned short* __restrict__ qkv,
                                                const float* __restrict__ zp,
                                                unsigned short* __restrict__ vt){
  constexpr int LD = 136;
  __shared__ __align__(16) unsigned short T[64*LD];
  __shared__ float invZ[64];
  const int p0 = blockIdx.x*64, n = blockIdx.y;
  const int t = threadIdx.x;
  size_t base = (size_t)n*384*4096;
  #pragma unroll
  for (int r=0;r<4;++r){
    int pi = t + 256*r; int pl = pi>>4, seg = pi&15;
    *(uint4*)&T[pl*LD + seg*8] = *(const uint4*)(qkv + base + (size_t)(p0+pl)*384 + 256 + seg*8);
  }
  if (t < 64){                            // merge zp partials for this block's 64 j
    float Z = 0.f;
    #pragma unroll
    for (int c=0;c<8;++c) Z += zp[(size_t)((n<<3)+c)*4096 + p0 + t];
    invZ[t] = 1.0f / Z;
  }
  __syncthreads();
  unsigned* vt32 = (unsigned*)(vt + (size_t)n*128*4096);
  #pragma unroll
  for (int r=0;r<16;++r){
    int pi = t + 256*r;            // 4096 = 128 d x 32 p-pairs
    int d = pi>>5, k = pi&31;
    float lo = bf2f(T[(2*k)*LD + d])   * invZ[2*k];
    float hi = bf2f(T[(2*k+1)*LD + d]) * invZ[2*k+1];
    vt32[(size_t)d*2048 + (p0>>1) + k] = bfpack(lo, hi);
  }
}

// ---------------- K4: PV pass — R4 verbatim (measured 56.3 us) ----------------
__global__ __launch_bounds__(256, 2) void k_attn(const unsigned short* __restrict__ qkv,
                                                 const unsigned short* __restrict__ vtg_all,
                                                 unsigned short* __restrict__ part){
  constexpr int LDK = 136, LDV = 72;
  __shared__ __align__(16) unsigned short Ks[2][64*LDK];    // 2 x 17408 B
  __shared__ __align__(16) unsigned short Vt[2][128*LDV];   // 2 x 18432 B   total 71680
  const int i0 = blockIdx.x*128, jh = blockIdx.y, n = blockIdx.z;
  const int t = threadIdx.x, w = t>>6, lane = t&63, lr = lane&15, q4 = lane>>4;
  size_t base = (size_t)n*384*4096;
  const unsigned short* vtg = vtg_all + (size_t)n*128*4096;
  bfrag qf[2][4];   // B[k=d][n=i] for 2 i-subtiles (register-resident)
  #pragma unroll
  for (int isub=0;isub<2;++isub){
    const unsigned short* qrow = qkv + base + (size_t)(i0 + w*32 + isub*16 + lr)*384;
    #pragma unroll
    for (int kk=0;kk<4;++kk) qf[isub][kk] = *(const bfrag*)(qrow + kk*32 + q4*8);
  }
  ffrag acc[8][2] = {};
  const float inv64 = 0.015625f;

  // staging addressing (tile-invariant parts)
  const int jl_k = t>>4, seg_k = t&15;          // K: 16 rows per r-step
  const int d_v  = t>>3, c_v  = t&7;            // V: 32 d-rows per r-step
  // shuffle source lanes: q4' = (2q4 + (m>>1)) & 3 ; m<2 -> sl0, m>=2 -> sl1
  const int sl0 = lr + 16*((2*q4)   & 3);
  const int sl1 = lr + 16*((2*q4+1) & 3);

  // prologue: stage tile 0 into buffer 0
  {
    const int j0 = jh*1024;
    #pragma unroll
    for (int r=0;r<4;++r)
      *(uint4*)&Ks[0][(jl_k+16*r)*LDK + seg_k*8] =
        *(const uint4*)(qkv + base + (size_t)(j0 + jl_k + 16*r)*384 + 128 + seg_k*8);
    #pragma unroll
    for (int r=0;r<4;++r)
      *(uint4*)&Vt[0][(d_v+32*r)*LDV + c_v*8] =
        *(const uint4*)(vtg + (size_t)(d_v + 32*r)*4096 + j0 + c_v*8);
  }
  __syncthreads();

  for (int it=0; it<16; ++it){
    const int cur = it & 1;
    // (1) issue next tile's global loads FIRST (latency hides under compute)
    uint4 kr[4], vr[4];
    if (it < 15){
      const int jn = jh*1024 + (it+1)*64;
      #pragma unroll
      for (int r=0;r<4;++r)
        kr[r] = *(const uint4*)(qkv + base + (size_t)(jn + jl_k + 16*r)*384 + 128 + seg_k*8);
      #pragma unroll
      for (int r=0;r<4;++r)
        vr[r] = *(const uint4*)(vtg + (size_t)(d_v + 32*r)*4096 + jn + c_v*8);
    }
    // (2) QK^T on current buffer; keep exp'd P packed in registers
    unsigned pk[4][2][2];   // [jt][isub][r-half]: (r0,r1),(r2,r3) bf16 pairs
    #pragma unroll
    for (int jt=0;jt<4;++jt){
      bfrag kf[4];
      #pragma unroll
      for (int kk=0;kk<4;++kk) kf[kk] = *(const bfrag*)&Ks[cur][(jt*16+lr)*LDK + kk*32 + q4*8]; // A[m=j][k=d]
      #pragma unroll
      for (int isub=0;isub<2;++isub){
        ffrag s = {};
        #pragma unroll
        for (int kk=0;kk<4;++kk) s = MFMA(kf[kk], qf[isub][kk], s);   // D[m=j][n=i]
        pk[jt][isub][0] = bfpack(__expf(s[0]*inv64), __expf(s[1]*inv64));
        pk[jt][isub][1] = bfpack(__expf(s[2]*inv64), __expf(s[3]*inv64));
      }
    }
    // (3) PV: redistribute P via shuffles (D rows q4*4+r -> B rows q4*8+e), then MFMA
    #pragma unroll
    for (int jk=0;jk<2;++jk){
      union { bfrag b; uint4 u; } pf0, pf1;
      unsigned v0[4], v1[4];
      #pragma unroll
      for (int m=0;m<4;++m){
        const int sl = (m<2) ? sl0 : sl1;
        unsigned a0 = __shfl(pk[2*jk  ][0][m&1], sl);
        unsigned b0 = __shfl(pk[2*jk+1][0][m&1], sl);
        v0[m] = (q4 >= 2) ? b0 : a0;
        unsigned a1 = __shfl(pk[2*jk  ][1][m&1], sl);
        unsigned b1 = __shfl(pk[2*jk+1][1][m&1], sl);
        v1[m] = (q4 >= 2) ? b1 : a1;
      }
      pf0.u = make_uint4(v0[0],v0[1],v0[2],v0[3]);
      pf1.u = make_uint4(v1[0],v1[1],v1[2],v1[3]);
      #pragma unroll
      for (int dt=0;dt<8;++dt){
        bfrag af = *(const bfrag*)&Vt[cur][(dt*16+lr)*LDV + jk*32 + q4*8]; // A[m=d][k=j]
        acc[dt][0] = MFMA(af, pf0.b, acc[dt][0]);   // D[m=d][n=i]
        acc[dt][1] = MFMA(af, pf1.b, acc[dt][1]);
      }
    }
    // (4) sink staged writes into the other buffer (vmcnt drain lands here, after compute)
    if (it < 15){
      #pragma unroll
      for (int r=0;r<4;++r) *(uint4*)&Ks[cur^1][(jl_k+16*r)*LDK + seg_k*8] = kr[r];
      #pragma unroll
      for (int r=0;r<4;++r) *(uint4*)&Vt[cur^1][(d_v+32*r)*LDV + c_v*8] = vr[r];
      __syncthreads();
    }
  }
  unsigned short* po = part + (size_t)(jh*4+n)*524288;
  #pragma unroll
  for (int isub=0;isub<2;++isub){
    const int i = i0 + w*32 + isub*16 + lr;
    #pragma unroll
    for (int dt=0;dt<8;++dt){
      us4 pko;
      pko.x = f2bf(acc[dt][isub][0]); pko.y = f2bf(acc[dt][isub][1]);
      pko.z = f2bf(acc[dt][isub][2]); pko.w = f2bf(acc[dt][isub][3]);
      *(us4*)(po + (size_t)i*128 + dt*16 + q4*4) = pko;
    }
  }
}

// ---------------- K5: output projection; Wo cast fused into As staging; Rt swizzled ----------------
__global__ __launch_bounds__(256) void k_oproj(const unsigned short* __restrict__ part,
                                               const float* __restrict__ Wo,
                                               const float* __restrict__ bo, float* __restrict__ y){
  constexpr int LD = 136;
  __shared__ __align__(16) unsigned short As[128*LD];  // Wo tile [c][e]
  __shared__ __align__(16) unsigned short Rt[64*LD];   // attn^T [hw][e], swizzled
  char* RtB = (char*)Rt;
  const int c0 = blockIdx.x*128, h0 = blockIdx.y*64, n = blockIdx.z;
  const int t = threadIdx.x, w = t>>6, lane = t&63, lr = lane&15, q4 = lane>>4;
  #pragma unroll
  for (int r=0;r<8;++r){                     // Wo cast+stage
    int pi = t + 256*r; int cl = pi>>4, seg = pi&15;
    const float* wsrc = Wo + (size_t)(c0+cl)*128 + seg*8;
    float4 w0 = *(const float4*)(wsrc);
    float4 w1 = *(const float4*)(wsrc+4);
    us4 lo, hv;
    lo.x=f2bf(w0.x); lo.y=f2bf(w0.y); lo.z=f2bf(w0.z); lo.w=f2bf(w0.w);
    hv.x=f2bf(w1.x); hv.y=f2bf(w1.y); hv.z=f2bf(w1.z); hv.w=f2bf(w1.w);
    *(us4*)&As[cl*LD + seg*8]     = lo;
    *(us4*)&As[cl*LD + seg*8 + 4] = hv;
  }
  #pragma unroll
  for (int r=0;r<4;++r){                     // 1024 = 128 e x 8 h-octets, uint4 loads
    int pi = t + 256*r; int e = pi>>3, h8 = pi&7;
    size_t f = (size_t)e*4096 + h0 + h8*8;
    float a[8] = {};
    #pragma unroll
    for (int s=0;s<4;++s){
      uint4 u = *(const uint4*)(part + (size_t)(s*4+n)*524288 + f);
      a[0] += bf2f((unsigned short)(u.x & 0xffffu)); a[1] += bf2f((unsigned short)(u.x >> 16));
      a[2] += bf2f((unsigned short)(u.y & 0xffffu)); a[3] += bf2f((unsigned short)(u.y >> 16));
      a[4] += bf2f((unsigned short)(u.z & 0xffffu)); a[5] += bf2f((unsigned short)(u.z >> 16));
      a[6] += bf2f((unsigned short)(u.w & 0xffffu)); a[7] += bf2f((unsigned short)(u.w >> 16));
    }
    #pragma unroll
    for (int u2=0;u2<8;++u2){
      int row = h8*8+u2;
      *(unsigned short*)(RtB + row*272 + ((2*e) ^ (((row>>3)&7)<<4))) = f2bf(a[u2]);
    }
  }
  __syncthreads();
  ffrag acc[8] = {};
  const int arow = w*16+lr;
  const int akey = ((arow>>3)&7)<<4;
  #pragma unroll
  for (int kk=0;kk<4;++kk){
    bfrag a = *(const bfrag*)(RtB + arow*272 + ((kk*64 + q4*16) ^ akey));  // A = attn^T rows (hw)
    #pragma unroll
    for (int cs=0;cs<8;++cs){
      bfrag b = *(const bfrag*)&As[(cs*16+lr)*LD + kk*32 + q4*8]; // B = Wo rows (c)
      acc[cs] = MFMA(a,b,acc[cs]);                                // D[m=hw][n=c]
    }
  }
  #pragma unroll
  for (int cs=0;cs<8;++cs){
    int c = c0 + cs*16 + lr;
    float bias = bo[c];
    float4 v4 = { acc[cs][0]+bias, acc[cs][1]+bias, acc[cs][2]+bias, acc[cs][3]+bias };
    *(float4*)(y + ((size_t)n*256 + c)*4096 + h0 + w*16 + q4*4) = v4;
  }
}

extern "C" void kernel_launch(void* const* d_in, const int* in_sizes, int n_in,
                              void* d_out, int out_size, void* d_ws, size_t ws_size,
                              hipStream_t stream){
  const float* x  = (const float*)d_in[0];
  const float* Wq = (const float*)d_in[1];
  const float* bq = (const float*)d_in[2];
  const float* Wo = (const float*)d_in[3];
  const float* bo = (const float*)d_in[4];
  float* y = (float*)d_out;
  char* ws = (char*)d_ws;
  unsigned short* qkv  = (unsigned short*)(ws + 0);          // 12,582,912
  unsigned short* vtg  = (unsigned short*)(ws + 12582912);   //  4,194,304
  float* zp   = (float*)(ws + 17039360);                     //    524,288 (4n x 8ic x 4096)
  unsigned short* part = (unsigned short*)(ws + 17629184);   // 16,777,216 (16 bf16 slices jh*4+n)

  k_qkv   <<<dim3(3,64,4),  256, 0, stream>>>(x, Wq, bq, qkv);
  k_stats <<<dim3(16,8,4),  256, 0, stream>>>(qkv, zp);
  k_vtrans<<<dim3(64,4),    256, 0, stream>>>(qkv, zp, vtg);
  k_attn  <<<dim3(32,4,4),  256, 0, stream>>>(qkv, vtg, part);
  k_oproj <<<dim3(2,64,4),  256, 0, stream>>>(part, Wo, bo, y);
}